// Round 5
// baseline (229.422 us; speedup 1.0000x reference)
//
#include <hip/hip_runtime.h>
#include <hip/hip_bf16.h>
#include <cstddef>
#include <cstdint>

typedef __attribute__((ext_vector_type(8))) short short8;
typedef __attribute__((ext_vector_type(16))) float float16;

#define C_CH 192
#define PK   9408      // C_CH * 49
#define D1   768

__device__ __forceinline__ ushort f2bf(float v) {
    return __builtin_bit_cast(unsigned short, __float2bfloat16(v));
}

// async global->LDS, 16B per lane, wave-uniform LDS base + lane*16 dest
__device__ __forceinline__ void gload16(const void* g, void* l) {
    __builtin_amdgcn_global_load_lds(
        (const __attribute__((address_space(1))) void*)g,
        (__attribute__((address_space(3))) void*)l, 16, 0, 0);
}

// ---------------------------------------------------------------------------
// fp32 -> bf16 conversion (standalone, used by fallback paths)
// ---------------------------------------------------------------------------
__global__ __launch_bounds__(256) void cvt_bf16_2(
    const float* __restrict__ in1, ushort* __restrict__ out1, int n4_1,
    const float* __restrict__ in2, ushort* __restrict__ out2, int n4_2)
{
    int i = blockIdx.x * 256 + threadIdx.x;
    const float* in; ushort* out;
    if (i < n4_1) { in = in1; out = out1; }
    else          { i -= n4_1; if (i >= n4_2) return; in = in2; out = out2; }
    float4 v = ((const float4*)in)[i];
    ushort4 o;
    o.x = f2bf(v.x); o.y = f2bf(v.y); o.z = f2bf(v.z); o.w = f2bf(v.w);
    ((ushort4*)out)[i] = o;
}

__global__ __launch_bounds__(256) void cvt_bf16(const float* __restrict__ in,
                                                ushort* __restrict__ out, int n4)
{
    int i = blockIdx.x * 256 + threadIdx.x;
    if (i >= n4) return;
    float4 v = ((const float4*)in)[i];
    ushort4 o;
    o.x = f2bf(v.x); o.y = f2bf(v.y); o.z = f2bf(v.z); o.w = f2bf(v.w);
    ((ushort4*)out)[i] = o;
}

// ---------------------------------------------------------------------------
// Fused pre-pass: all 4 pyramid levels NCHW(fp32) -> NHWC(bf16) with
// coalesced dword stores, PLUS fp32->bf16 conversion of both weight
// tensors in extra blocks of the same grid. One launch.
// ---------------------------------------------------------------------------
__global__ __launch_bounds__(256) void fused_pre(
    const float* __restrict__ f0, const float* __restrict__ f1,
    const float* __restrict__ f2, const float* __restrict__ f3,
    ushort* __restrict__ o0, ushort* __restrict__ o1,
    ushort* __restrict__ o2, ushort* __restrict__ o3,
    const float* __restrict__ w1src, ushort* __restrict__ w1dst, int n41,
    const float* __restrict__ w2src, ushort* __restrict__ w2dst, int n42,
    int nTrans)
{
    __shared__ unsigned int sm[96][33];   // 96 channel-pairs x 32 px (+1 pad)

    int bx = blockIdx.x;
    if (bx >= nTrans) {
        int i = (bx - nTrans) * 256 + threadIdx.x;
        const float* in; ushort* out;
        if (i < n41) { in = w1src; out = w1dst; }
        else         { i -= n41; if (i >= n42) return; in = w2src; out = w2dst; }
        float4 v = ((const float4*)in)[i];
        ushort4 o;
        o.x = f2bf(v.x); o.y = f2bf(v.y); o.z = f2bf(v.z); o.w = f2bf(v.w);
        ((ushort4*)out)[i] = o;
        return;
    }

    int b = bx / 680;
    int t = bx - b * 680;
    const float* in; ushort* out; int HW, hw0;
    if      (t < 512) { in = f0; out = o0; HW = 16384; hw0 = t * 32; }
    else if (t < 640) { in = f1; out = o1; HW = 4096;  hw0 = (t - 512) * 32; }
    else if (t < 672) { in = f2; out = o2; HW = 1024;  hw0 = (t - 640) * 32; }
    else              { in = f3; out = o3; HW = 256;   hw0 = (t - 672) * 32; }

    int tx = threadIdx.x & 31;
    int ty = threadIdx.x >> 5;    // 0..7

    const float* ip = in + (size_t)b * C_CH * HW + hw0;
    #pragma unroll
    for (int it = 0; it < 12; ++it) {          // 96 pairs = 12 * 8
        int cp = it * 8 + ty;
        float v0 = ip[(size_t)(2 * cp)     * HW + tx];
        float v1 = ip[(size_t)(2 * cp + 1) * HW + tx];
        sm[cp][tx] = (unsigned int)f2bf(v0) | ((unsigned int)f2bf(v1) << 16);
    }
    __syncthreads();

    unsigned int* op = (unsigned int*)(out + ((size_t)b * HW + hw0) * C_CH);
    #pragma unroll
    for (int it = 0; it < 12; ++it) {          // 32 px * 96 dwords = 12 * 256
        int idx = it * 256 + (int)threadIdx.x;
        int r = idx / 96;
        int p = idx - r * 96;
        op[idx] = sm[p][r];
    }
}

// ---------------------------------------------------------------------------
// RoIAlign gather from NHWC bf16, one block per RoI (r4 structure, proven
// at its latency floor: further VMEM-count reductions were null).
// ---------------------------------------------------------------------------
__device__ __forceinline__ void issue8(
    const char* sbase, const int (*offB)[4], int s2, int c16, float4* u)
{
    #pragma unroll
    for (int k = 0; k < 8; ++k) {
        int s  = s2 + (k >> 2);
        int tp = k & 3;
        u[k] = *(const float4*)(sbase + (offB[s][tp] + c16));
    }
}

__device__ __forceinline__ void comp8(
    const float4* u, const float (*wt)[4], int s2, float* a)
{
    #pragma unroll
    for (int k = 0; k < 8; ++k) {
        float w = wt[s2 + (k >> 2)][k & 3];
        unsigned int u0 = __builtin_bit_cast(unsigned int, u[k].x);
        unsigned int u1 = __builtin_bit_cast(unsigned int, u[k].y);
        unsigned int u2 = __builtin_bit_cast(unsigned int, u[k].z);
        unsigned int u3 = __builtin_bit_cast(unsigned int, u[k].w);
        a[0] = fmaf(__builtin_bit_cast(float, u0 << 16),         w, a[0]);
        a[1] = fmaf(__builtin_bit_cast(float, u0 & 0xffff0000u), w, a[1]);
        a[2] = fmaf(__builtin_bit_cast(float, u1 << 16),         w, a[2]);
        a[3] = fmaf(__builtin_bit_cast(float, u1 & 0xffff0000u), w, a[3]);
        a[4] = fmaf(__builtin_bit_cast(float, u2 << 16),         w, a[4]);
        a[5] = fmaf(__builtin_bit_cast(float, u2 & 0xffff0000u), w, a[5]);
        a[6] = fmaf(__builtin_bit_cast(float, u3 << 16),         w, a[6]);
        a[7] = fmaf(__builtin_bit_cast(float, u3 & 0xffff0000u), w, a[7]);
    }
}

__global__ __launch_bounds__(384, 3) void roi_gather(
    const ushort* __restrict__ n0p, const ushort* __restrict__ n1p,
    const ushort* __restrict__ n2p, const ushort* __restrict__ n3p,
    const float* __restrict__ rois, ushort* __restrict__ pooled)
{
    __shared__ int    s_offB[196][4];   // global byte offsets
    __shared__ float  s_w[196][4];
    __shared__ ushort s_out[PK];        // 192 channels x 49 bins

    const int n   = blockIdx.x;
    const int tid = threadIdx.x;

    float by1 = rois[n*5+0], bx1 = rois[n*5+1];
    float by2 = rois[n*5+2], bx2 = rois[n*5+3];
    int   b   = (int)rois[n*5+4];

    float hh = by2 - by1, ww = bx2 - bx1;
    int lvl = (int)rintf(4.0f + log2f(sqrtf(hh * ww)));
    lvl = min(max(lvl, 0), 3);

    const ushort* fm; int H;
    if      (lvl == 0) { fm = n0p; H = 128; }
    else if (lvl == 1) { fm = n1p; H = 64;  }
    else if (lvl == 2) { fm = n2p; H = 32;  }
    else               { fm = n3p; H = 16;  }
    float Hf = (float)H;

    float y1p = by1 * Hf, x1p = bx1 * Hf;
    float y2p = by2 * Hf, x2p = bx2 * Hf;
    float bin_h = fmaxf(y2p - y1p, 1.0f) * (1.0f / 7.0f);
    float bin_w = fmaxf(x2p - x1p, 1.0f) * (1.0f / 7.0f);

    // scalarize base pointer (block-uniform): SGPR base + 32-bit voffset loads
    uintptr_t bp = (uintptr_t)(fm + (size_t)b * H * H * C_CH);
    unsigned int blo = __builtin_amdgcn_readfirstlane((unsigned int)bp);
    unsigned int bhi = __builtin_amdgcn_readfirstlane((unsigned int)(bp >> 32));
    const char* sbase = (const char*)((((uintptr_t)bhi) << 32) | blo);

    if (tid < 196) {
        int s = tid;
        int sx = s & 1, sy = (s >> 1) & 1, ij = s >> 2;
        int i = ij / 7, j = ij - i * 7;

        float gy = (float)i + 0.25f + 0.5f * (float)sy;
        float y  = y1p + gy * bin_h;
        bool  vy = (y >= -1.0f) && (y <= Hf);
        float yc = fminf(fmaxf(y, 0.0f), Hf - 1.0f);
        int   y0 = (int)floorf(yc);
        float ly = yc - (float)y0;
        int   y1i = min(y0 + 1, H - 1);

        float gx = (float)j + 0.25f + 0.5f * (float)sx;
        float x  = x1p + gx * bin_w;
        bool  vx = (x >= -1.0f) && (x <= Hf);
        float xc = fminf(fmaxf(x, 0.0f), Hf - 1.0f);
        int   x0 = (int)floorf(xc);
        float lx = xc - (float)x0;
        int   x1i = min(x0 + 1, H - 1);

        float vm = (vy && vx) ? 0.25f : 0.0f;
        s_offB[s][0] = (y0  * H + x0 ) * (C_CH * 2);
        s_offB[s][1] = (y0  * H + x1i) * (C_CH * 2);
        s_offB[s][2] = (y1i * H + x0 ) * (C_CH * 2);
        s_offB[s][3] = (y1i * H + x1i) * (C_CH * 2);
        s_w[s][0] = (1.0f - ly) * (1.0f - lx) * vm;
        s_w[s][1] = (1.0f - ly) * lx * vm;
        s_w[s][2] = ly * (1.0f - lx) * vm;
        s_w[s][3] = ly * lx * vm;
    }
    __syncthreads();

    const int grp = tid / 24;            // 0..15 bin-group
    const int ci  = tid - grp * 24;      // channel-oct index
    const int cl  = ci * 8;              // channel in [0,192)
    const int c16 = ci * 16;             // byte offset of channel oct
    const int bin_lo = (grp * 49) >> 4;  // 3 or 4 bins per group
    const int bin_hi = ((grp + 1) * 49) >> 4;

    float4 ua[8], ub[8];
    float  a[8];

    // chunk = half-bin = 2 subsamples = 8 taps
    issue8(sbase, s_offB, bin_lo * 4, c16, ua);
    for (int bin = bin_lo; bin < bin_hi; ++bin) {
        issue8(sbase, s_offB, bin * 4 + 2, c16, ub);     // second half of bin
        #pragma unroll
        for (int k = 0; k < 8; ++k) a[k] = 0.0f;
        comp8(ua, s_w, bin * 4, a);
        if (bin + 1 < bin_hi)
            issue8(sbase, s_offB, (bin + 1) * 4, c16, ua); // next bin, first half
        comp8(ub, s_w, bin * 4 + 2, a);
        #pragma unroll
        for (int k = 0; k < 8; ++k)
            s_out[(cl + k) * 49 + bin] = f2bf(a[k]);
    }
    __syncthreads();

    unsigned int* po = (unsigned int*)(pooled + (size_t)n * PK);
    const unsigned int* so = (const unsigned int*)s_out;
    for (int idx = tid; idx < PK / 2; idx += 384) po[idx] = so[idx];
}

// ---------------------------------------------------------------------------
// RoIAlign from NCHW fp32 (fallback path, proven): 1 thread / output element
// ---------------------------------------------------------------------------
__global__ __launch_bounds__(256) void roi_align_nchw(
    const float* __restrict__ f0, const float* __restrict__ f1,
    const float* __restrict__ f2, const float* __restrict__ f3,
    const float* __restrict__ rois, ushort* __restrict__ pooled, int n_rois)
{
    int idx = blockIdx.x * 256 + threadIdx.x;
    if (idx >= n_rois * PK) return;
    int n  = idx / PK;
    int r  = idx - n * PK;
    int c  = r / 49;
    int ij = r - c * 49;
    int i  = ij / 7;
    int j  = ij - i * 7;

    float by1 = rois[n*5+0], bx1 = rois[n*5+1];
    float by2 = rois[n*5+2], bx2 = rois[n*5+3];
    int   b   = (int)rois[n*5+4];

    float hh = by2 - by1, ww = bx2 - bx1;
    int lvl = (int)rintf(4.0f + log2f(sqrtf(hh * ww)));
    lvl = min(max(lvl, 0), 3);

    const float* fmap; int H;
    if      (lvl == 0) { fmap = f0; H = 128; }
    else if (lvl == 1) { fmap = f1; H = 64;  }
    else if (lvl == 2) { fmap = f2; H = 32;  }
    else               { fmap = f3; H = 16;  }
    float Hf = (float)H;

    float y1p = by1 * Hf, x1p = bx1 * Hf;
    float bin_h = fmaxf(by2 * Hf - y1p, 1.0f) * (1.0f / 7.0f);
    float bin_w = fmaxf(bx2 * Hf - x1p, 1.0f) * (1.0f / 7.0f);

    const float* base = fmap + ((size_t)b * C_CH + c) * (size_t)(H * H);

    float acc = 0.0f;
    #pragma unroll
    for (int sy = 0; sy < 2; ++sy) {
        float y  = y1p + ((float)i + 0.25f + 0.5f * (float)sy) * bin_h;
        bool  vy = (y >= -1.0f) && (y <= Hf);
        float yc = fminf(fmaxf(y, 0.0f), Hf - 1.0f);
        int   y0 = (int)floorf(yc);
        float ly = yc - (float)y0;
        int   y1i = min(y0 + 1, H - 1);
        #pragma unroll
        for (int sx = 0; sx < 2; ++sx) {
            float x  = x1p + ((float)j + 0.25f + 0.5f * (float)sx) * bin_w;
            bool  vx = (x >= -1.0f) && (x <= Hf);
            float xc = fminf(fmaxf(x, 0.0f), Hf - 1.0f);
            int   x0 = (int)floorf(xc);
            float lx = xc - (float)x0;
            int   x1i = min(x0 + 1, H - 1);
            if (vy && vx) {
                float v = base[y0 * H + x0 ] * (1.0f - ly) * (1.0f - lx)
                        + base[y0 * H + x1i] * (1.0f - ly) * lx
                        + base[y1i * H + x0 ] * ly * (1.0f - lx)
                        + base[y1i * H + x1i] * ly * lx;
                acc += v;
            }
        }
    }
    pooled[idx] = f2bf(acc * 0.25f);
}

// ---------------------------------------------------------------------------
// bf16 MFMA GEMM, 64x64 tile (proven, reg-staged). MODE 0: fp32 out
// bias+relu. MODE 1: bf16 out bias+relu. MODE 2: fp32 partial split-K.
// ---------------------------------------------------------------------------
template<int MODE>
__global__ __launch_bounds__(256) void mfma_gemm(
    const ushort* __restrict__ A, const ushort* __restrict__ W,
    const float* __restrict__ bias, void* __restrict__ outp,
    int M, int N, int K, int nkPer, int nkTotal)
{
    __shared__ char ldsA[2][8192];
    __shared__ char ldsB[2][8192];

    const int t    = threadIdx.x;
    const int lane = t & 63;
    const int wave = t >> 6;
    const int wm = wave >> 1, wn = wave & 1;

    const int m0 = blockIdx.y * 64;
    const int n0 = blockIdx.x * 64;
    const int kb = (MODE == 2) ? blockIdx.z * nkPer : 0;
    const int nk = (MODE == 2) ? min(nkPer, nkTotal - kb) : nkPer;

    const int ks   = t & 3;
    const int mrow = t >> 2;
    const int g    = mrow >> 5;
    const int rw   = mrow & 31;
    const int lof0 = ks*2048 + g*1024 + ((     rw) ^ (ks<<2))*16;
    const int lof1 = ks*2048 + g*1024 + ((32 + rw) ^ (ks<<2))*16;

    const int arow = min(m0 + mrow, M-1);
    const int brow = n0 + mrow;
    const ushort* ap = A + (size_t)arow * K + (size_t)kb * 64 + ks*16;
    const ushort* bp = W + (size_t)brow * K + (size_t)kb * 64 + ks*16;

    float4 ra0, ra1, rb0, rb1;
    float4 qa0, qa1, qb0, qb1;

    ra0 = ((const float4*)ap)[0]; ra1 = ((const float4*)ap)[1];
    rb0 = ((const float4*)bp)[0]; rb1 = ((const float4*)bp)[1];
    *(float4*)&ldsA[0][lof0] = ra0; *(float4*)&ldsA[0][lof1] = ra1;
    *(float4*)&ldsB[0][lof0] = rb0; *(float4*)&ldsB[0][lof1] = rb1;
    {
        int k1 = min(1, nk - 1);
        const ushort* ap1 = ap + (size_t)k1 * 64;
        const ushort* bp1 = bp + (size_t)k1 * 64;
        ra0 = ((const float4*)ap1)[0]; ra1 = ((const float4*)ap1)[1];
        rb0 = ((const float4*)bp1)[0]; rb1 = ((const float4*)bp1)[1];
    }
    __syncthreads();

    float16 acc = {};

    for (int kt = 0; kt < nk; ++kt) {
        {
            int k2 = min(kt + 2, nk - 1);
            const ushort* ap2 = ap + (size_t)k2 * 64;
            const ushort* bp2 = bp + (size_t)k2 * 64;
            qa0 = ((const float4*)ap2)[0]; qa1 = ((const float4*)ap2)[1];
            qb0 = ((const float4*)bp2)[0]; qb1 = ((const float4*)bp2)[1];
        }
        if (kt + 1 < nk) {
            char* dA = ldsA[(kt+1)&1]; char* dB = ldsB[(kt+1)&1];
            *(float4*)&dA[lof0] = ra0; *(float4*)&dA[lof1] = ra1;
            *(float4*)&dB[lof0] = rb0; *(float4*)&dB[lof1] = rb1;
        }
        const char* sA = ldsA[kt&1]; const char* sB = ldsB[kt&1];
        #pragma unroll
        for (int s = 0; s < 4; ++s) {
            int ro = s*2048 + (lane ^ (s<<2))*16;
            short8 af = *(const short8*)&sA[wm*1024 + ro];
            short8 bf = *(const short8*)&sB[wn*1024 + ro];
            acc = __builtin_amdgcn_mfma_f32_32x32x16_bf16(af, bf, acc, 0, 0, 0);
        }
        __syncthreads();
        ra0 = qa0; ra1 = qa1; rb0 = qb0; rb1 = qb1;
    }

    const int col   = lane & 31;
    const int rbase = 4 * (lane >> 5);
    const int nG    = n0 + wn*32 + col;

    if (MODE == 2) {
        float* O = (float*)outp + (size_t)blockIdx.z * M * N;
        #pragma unroll
        for (int r = 0; r < 16; ++r) {
            int row = (r & 3) + 8*(r >> 2) + rbase;
            int mG  = m0 + wm*32 + row;
            if (mG < M) O[(size_t)mG * N + nG] = acc[r];
        }
    } else if (MODE == 1) {
        const float bv = bias[nG];
        ushort* O = (ushort*)outp;
        #pragma unroll
        for (int r = 0; r < 16; ++r) {
            int row = (r & 3) + 8*(r >> 2) + rbase;
            int mG  = m0 + wm*32 + row;
            if (mG < M) O[(size_t)mG * N + nG] = f2bf(fmaxf(acc[r] + bv, 0.0f));
        }
    } else {
        const float bv = bias[nG];
        float* O = (float*)outp;
        #pragma unroll
        for (int r = 0; r < 16; ++r) {
            int row = (r & 3) + 8*(r >> 2) + rbase;
            int mG  = m0 + wm*32 + row;
            if (mG < M) O[(size_t)mG * N + nG] = fmaxf(acc[r] + bv, 0.0f);
        }
    }
}

// ---------------------------------------------------------------------------
// bf16 MFMA GEMM, 128x128 tile, BK=64, double-buffered LDS.
// Staging via global_load_lds dwordx4 DMA (m97 pattern): LDS dest is linear
// per 1KB segment; the XOR swizzle is baked into the per-lane GLOBAL source
// address (write perm == read perm, rule #21). 4 waves x (4 A + 4 B)
// segments per K-step. fp32 partial out, ragged split-K.
// ---------------------------------------------------------------------------
__global__ __launch_bounds__(256) void mfma_gemm128(
    const ushort* __restrict__ A, const ushort* __restrict__ W,
    void* __restrict__ outp, int M, int N, int K, int nkPer, int nkTotal)
{
    __shared__ char ldsA[2][16384];
    __shared__ char ldsB[2][16384];

    const int t    = threadIdx.x;
    const int lane = t & 63;
    const int wave = t >> 6;
    const int wm = wave >> 1, wn = wave & 1;

    const int m0 = blockIdx.y * 128;
    const int n0 = blockIdx.x * 128;
    const int kb = blockIdx.z * nkPer;
    const int nk = min(nkPer, nkTotal - kb);

    // Segment sid = wave*4 + i (16 x 1KB per buffer):
    //   ks = sid>>2 (K-quarter), h = (sid>>1)&1 (row-half), g = sid&1 (row-32-block)
    //   swz = ks<<2 ; lane slot holds:
    //     row_local = h*64 + g*32 + ((lane&31)^swz)
    //     k-half    = (lane>>5)*8  within the 16-elem K-quarter
    int aoff[4], boff[4], lofs[4];
    #pragma unroll
    for (int i = 0; i < 4; ++i) {
        int sid = wave * 4 + i;
        int ks = sid >> 2, h = (sid >> 1) & 1, g = sid & 1;
        int swz = ks << 2;
        int rl  = h * 64 + g * 32 + ((lane & 31) ^ swz);
        int ko  = ks * 16 + (lane >> 5) * 8;
        int arow = min(m0 + rl, M - 1);
        int brow = n0 + rl;          // N grid is exact
        aoff[i] = arow * K + ko;
        boff[i] = brow * K + ko;
        lofs[i] = sid * 1024;
    }
    const size_t kbase = (size_t)kb * 64;

    #define STAGE128(buf, kt)                                                  \
        do {                                                                   \
            const ushort* Ab_ = A + kbase + (size_t)(kt) * 64;                 \
            const ushort* Wb_ = W + kbase + (size_t)(kt) * 64;                 \
            _Pragma("unroll")                                                  \
            for (int i_ = 0; i_ < 4; ++i_) {                                   \
                gload16(Ab_ + aoff[i_], &ldsA[buf][lofs[i_]]);                 \
                gload16(Wb_ + boff[i_], &ldsB[buf][lofs[i_]]);                 \
            }                                                                  \
        } while (0)

    STAGE128(0, 0);
    __syncthreads();

    float16 acc00 = {}, acc01 = {}, acc10 = {}, acc11 = {};

    for (int kt = 0; kt < nk; ++kt) {
        if (kt + 1 < nk) STAGE128((kt + 1) & 1, kt + 1);
        const char* sA = ldsA[kt & 1];
        const char* sB = ldsB[kt & 1];
        #pragma unroll
        for (int s = 0; s < 4; ++s) {
            int ro = s*4096 + (lane ^ (s<<2))*16;
            short8 a0 = *(const short8*)&sA[wm*2048        + ro];
            short8 a1 = *(const short8*)&sA[wm*2048 + 1024 + ro];
            short8 b0 = *(const short8*)&sB[wn*2048        + ro];
            short8 b1 = *(const short8*)&sB[wn*2048 + 1024 + ro];
            acc00 = __builtin_amdgcn_mfma_f32_32x32x16_bf16(a0, b0, acc00, 0, 0, 0);
            acc01 = __builtin_amdgcn_mfma_f32_32x32x16_bf16(a0, b1, acc01, 0, 0, 0);
            acc10 = __builtin_amdgcn_mfma_f32_32x32x16_bf16(a1, b0, acc10, 0, 0, 0);
            acc11 = __builtin_amdgcn_mfma_f32_32x32x16_bf16(a1, b1, acc11, 0, 0, 0);
        }
        __syncthreads();
    }
    #undef STAGE128

    const int col   = lane & 31;
    const int rbase = 4 * (lane >> 5);
    float* O = (float*)outp + (size_t)blockIdx.z * M * N;

    const int mb0 = m0 + wm*64;
    const int nb0 = n0 + wn*64;
    #pragma unroll
    for (int r = 0; r < 16; ++r) {
        int row = (r & 3) + 8*(r >> 2) + rbase;
        int mG0 = mb0 + row;
        int mG1 = mb0 + 32 + row;
        int nG0 = nb0 + col;
        int nG1 = nb0 + 32 + col;
        if (mG0 < M) {
            O[(size_t)mG0 * N + nG0] = acc00[r];
            O[(size_t)mG0 * N + nG1] = acc01[r];
        }
        if (mG1 < M) {
            O[(size_t)mG1 * N + nG0] = acc10[r];
            O[(size_t)mG1 * N + nG1] = acc11[r];
        }
    }
}

// ---------------------------------------------------------------------------
// FC1 split-K reduce -> bf16 Y
// ---------------------------------------------------------------------------
__global__ __launch_bounds__(256) void reduce_relu_bf16(
    const float* __restrict__ P, const float* __restrict__ bias,
    ushort* __restrict__ Y, int MN, int N, int S)
{
    int idx = blockIdx.x * 256 + threadIdx.x;
    if (idx >= MN / 4) return;
    float4 s = ((const float4*)P)[idx];
    for (int k = 1; k < S; ++k) {
        float4 p = ((const float4*)(P + (size_t)k * MN))[idx];
        s.x += p.x; s.y += p.y; s.z += p.z; s.w += p.w;
    }
    int n4 = idx % (N / 4);
    float4 bv = ((const float4*)bias)[n4];
    ushort4 o;
    o.x = f2bf(fmaxf(s.x + bv.x, 0.0f));
    o.y = f2bf(fmaxf(s.y + bv.y, 0.0f));
    o.z = f2bf(fmaxf(s.z + bv.z, 0.0f));
    o.w = f2bf(fmaxf(s.w + bv.w, 0.0f));
    ((ushort4*)Y)[idx] = o;
}

// ---------------------------------------------------------------------------
// Fused FC2-reduce + relu + heads. One block per RoI (256 threads).
// ---------------------------------------------------------------------------
__global__ __launch_bounds__(256) void reduce_heads(
    const float* __restrict__ P2, const float* __restrict__ b2, int S, int MN,
    const float* __restrict__ w_bbox, const float* __restrict__ b_bbox,
    const float* __restrict__ w_cls,  const float* __restrict__ b_cls,
    const float* __restrict__ w_reg,  const float* __restrict__ b_reg,
    const float* __restrict__ w_unc,  const float* __restrict__ b_unc,
    float* __restrict__ out, int n_rois)
{
    __shared__ float zrow[D1];
    const int m   = blockIdx.x;
    const int tid = threadIdx.x;

    const float* Pm = P2 + (size_t)m * D1;
    #pragma unroll
    for (int r = 0; r < 3; ++r) {               // 768 = 3 * 256
        int k = r * 256 + tid;
        float v = Pm[k];
        for (int s = 1; s < S; ++s) v += Pm[(size_t)s * MN + k];
        zrow[k] = fmaxf(v + b2[k], 0.0f);
    }
    __syncthreads();

    const int wave = tid >> 6;
    const int lane = tid & 63;
    for (int o = wave; o < 14; o += 4) {
        const float* w; float bb;
        if      (o < 8)  { w = w_bbox + o * D1;        bb = b_bbox[o]; }
        else if (o < 10) { w = w_cls  + (o - 8) * D1;  bb = b_cls[o - 8]; }
        else if (o < 12) { w = w_reg  + (o - 10) * D1; bb = b_reg[o - 10]; }
        else             { w = w_unc  + (o - 12) * D1; bb = b_unc[o - 12]; }
        float p = 0.0f;
        #pragma unroll
        for (int r = 0; r < 12; ++r) {          // 768 = 12 * 64
            int k = r * 64 + lane;
            p = fmaf(zrow[k], w[k], p);
        }
        #pragma unroll
        for (int d = 32; d >= 1; d >>= 1) p += __shfl_down(p, d, 64);
        if (lane == 0) {
            int off;
            int clsOff = n_rois * 8;
            int regOff = n_rois * 10;
            if      (o < 8)  off = m * 8 + o;
            else if (o < 10) off = clsOff + m * 2 + (o - 8);
            else if (o < 12) off = regOff + m * 4 + (o - 10) * 2;
            else             off = regOff + m * 4 + (o - 12) * 2 + 1;
            out[off] = p + bb;
        }
    }
}

// ---------------------------------------------------------------------------
// Heads (fallback path)
// ---------------------------------------------------------------------------
__global__ __launch_bounds__(256) void heads_kernel(
    const float* __restrict__ Z,
    const float* __restrict__ w_bbox, const float* __restrict__ b_bbox,
    const float* __restrict__ w_cls,  const float* __restrict__ b_cls,
    const float* __restrict__ w_reg,  const float* __restrict__ b_reg,
    const float* __restrict__ w_unc,  const float* __restrict__ b_unc,
    float* __restrict__ out, int n_rois)
{
    int idx = blockIdx.x * 256 + threadIdx.x;
    if (idx >= n_rois * 14) return;
    int n = idx / 14;
    int o = idx - n * 14;

    const float* w; float bb;
    if      (o < 8)  { w = w_bbox + o * D1;        bb = b_bbox[o]; }
    else if (o < 10) { w = w_cls  + (o - 8) * D1;  bb = b_cls[o - 8]; }
    else if (o < 12) { w = w_reg  + (o - 10) * D1; bb = b_reg[o - 10]; }
    else             { w = w_unc  + (o - 12) * D1; bb = b_unc[o - 12]; }

    const float* z = Z + (size_t)n * D1;
    float s = bb;
    for (int k = 0; k < D1; k += 4) {
        float4 zv = *(const float4*)(z + k);
        float4 wv = *(const float4*)(w + k);
        s = fmaf(zv.x, wv.x, s);
        s = fmaf(zv.y, wv.y, s);
        s = fmaf(zv.z, wv.z, s);
        s = fmaf(zv.w, wv.w, s);
    }

    int off;
    int clsOff = n_rois * 8;
    int regOff = n_rois * 10;
    if      (o < 8)  off = n * 8 + o;
    else if (o < 10) off = clsOff + n * 2 + (o - 8);
    else if (o < 12) off = regOff + n * 4 + (o - 10) * 2;
    else             off = regOff + n * 4 + (o - 12) * 2 + 1;
    out[off] = s;
}

// ---------------------------------------------------------------------------
extern "C" void kernel_launch(void* const* d_in, const int* in_sizes, int n_in,
                              void* d_out, int out_size, void* d_ws, size_t ws_size,
                              hipStream_t stream)
{
    const float* f0   = (const float*)d_in[0];
    const float* f1   = (const float*)d_in[1];
    const float* f2   = (const float*)d_in[2];
    const float* f3   = (const float*)d_in[3];
    const float* rois = (const float*)d_in[4];
    const float* w1   = (const float*)d_in[5];
    const float* b1   = (const float*)d_in[6];
    const float* w2   = (const float*)d_in[7];
    const float* b2   = (const float*)d_in[8];
    const float* w_bbox = (const float*)d_in[9];
    const float* b_bbox = (const float*)d_in[10];
    const float* w_cls  = (const float*)d_in[11];
    const float* b_cls  = (const float*)d_in[12];
    const float* w_reg  = (const float*)d_in[13];
    const float* b_reg  = (const float*)d_in[14];
    const float* w_unc  = (const float*)d_in[15];
    const float* b_unc  = (const float*)d_in[16];
    float* out = (float*)d_out;

    const int n_rois = in_sizes[4] / 5;                  // 1000
    const int B      = in_sizes[0] / (C_CH * 128 * 128); // 4

    const size_t nh0B = (size_t)B * 16384 * C_CH * 2;
    const size_t nh1B = (size_t)B * 4096  * C_CH * 2;
    const size_t nh2B = (size_t)B * 1024  * C_CH * 2;
    const size_t nh3B = (size_t)B * 256   * C_CH * 2;
    const size_t nhAll = nh0B + nh1B + nh2B + nh3B;      // 33.4 MB
    const size_t poolB = (size_t)n_rois * PK * 2;        // 18.8 MB
    const size_t w1Bb  = (size_t)D1 * PK * 2;            // 14.45 MB
    const size_t w2Bb  = (size_t)D1 * D1 * 2;
    const size_t Yb    = (size_t)n_rois * D1 * 2;
    const size_t Zb    = (size_t)n_rois * D1 * 4;
    const size_t smallB = w2Bb + Yb + Zb;

    const int SPLIT1  = 10;  // FC1 (128-tile): nkPer=15 -> 15x9 + 12 (147)
    const int SPLIT1F = 5;   // FC1 (64-tile fallback plan)
    const int SPLIT2  = 2;   // FC2: 6+6

    const size_t P1b   = (size_t)SPLIT1 * n_rois * D1 * 4;   // 30.7 MB (<= nhAll)
    const size_t needX2 = nhAll + poolB + w1Bb + w2Bb + Yb;  // ~69.4 MB
    const size_t needX  = nhAll + poolB + smallB;            // ~58.0 MB (proven)

    char* ws = (char*)d_ws;

    int n41 = D1*PK/4, n42 = D1*D1/4;

    if (ws_size >= needX2) {
        // ---------------- Plan X2: fused pre-pass + gload_lds 128-tile FC1 -
        ushort* nh0 = (ushort*)ws;
        ushort* nh1 = nh0 + nh0B/2;
        ushort* nh2 = nh1 + nh1B/2;
        ushort* nh3 = nh2 + nh2B/2;
        ushort* pooledB = (ushort*)(ws + nhAll);
        ushort* w1B = (ushort*)(ws + nhAll + poolB);
        ushort* w2B = (ushort*)(ws + nhAll + poolB + w1Bb);
        ushort* Y   = (ushort*)(ws + nhAll + poolB + w1Bb + w2Bb);
        float*  P   = (float*)ws;                // alias: nh dead after gather
        float*  P2  = (float*)(ws + P1b);        // alias: pooled dead after FC1

        int nTrans = 680 * B;
        int nCvt   = (n41 + n42 + 255) / 256;
        fused_pre<<<nTrans + nCvt, 256, 0, stream>>>(
            f0, f1, f2, f3, nh0, nh1, nh2, nh3,
            w1, w1B, n41, w2, w2B, n42, nTrans);

        roi_gather<<<n_rois, 384, 0, stream>>>(nh0, nh1, nh2, nh3, rois, pooledB);

        {
            int nkTotal = PK / 64;                          // 147
            int nkPer   = (nkTotal + SPLIT1 - 1) / SPLIT1;  // 15
            dim3 grid(D1/128, (n_rois + 127)/128, SPLIT1);
            mfma_gemm128<<<grid, 256, 0, stream>>>(pooledB, w1B, P,
                                                   n_rois, D1, PK, nkPer, nkTotal);
            int MN = n_rois * D1;
            reduce_relu_bf16<<<(MN/4 + 255)/256, 256, 0, stream>>>(P, b1, Y, MN, D1, SPLIT1);
        }
        {
            int nkTotal = D1 / 64;                          // 12
            int nkPer   = nkTotal / SPLIT2;                 // 6
            dim3 grid(D1/64, (n_rois + 63)/64, SPLIT2);
            mfma_gemm<2><<<grid, 256, 0, stream>>>(Y, w2B, nullptr, P2,
                                                   n_rois, D1, D1, nkPer, nkTotal);
            int MN = n_rois * D1;
            reduce_heads<<<n_rois, 256, 0, stream>>>(P2, b2, SPLIT2, MN,
                w_bbox, b_bbox, w_cls, b_cls, w_reg, b_reg, w_unc, b_unc, out, n_rois);
        }
    } else if (ws_size >= needX) {
        // ---------------- Plan X (previous proven layout) ----------------
        ushort* nh0 = (ushort*)ws;
        ushort* nh1 = nh0 + nh0B/2;
        ushort* nh2 = nh1 + nh1B/2;
        ushort* nh3 = nh2 + nh2B/2;
        ushort* w1B = (ushort*)ws;                  // alias after gather
        float*  P   = (float*)(ws + w1Bb);          // alias after gather
        float*  P2  = (float*)ws;                   // alias after FC1 gemm
        ushort* pooledB = (ushort*)(ws + nhAll);
        ushort* w2B = (ushort*)(ws + nhAll + poolB);
        ushort* Y   = w2B + w2Bb/2;

        int nTrans = 680 * B;
        fused_pre<<<nTrans, 256, 0, stream>>>(
            f0, f1, f2, f3, nh0, nh1, nh2, nh3,
            w1, (ushort*)nullptr, 0, w2, (ushort*)nullptr, 0, nTrans);
        roi_gather<<<n_rois, 384, 0, stream>>>(nh0, nh1, nh2, nh3, rois, pooledB);
        cvt_bf16_2<<<(n41 + n42 + 255)/256, 256, 0, stream>>>(
            w1, w1B, n41, w2, w2B, n42);
        {
            int nkTotal = PK / 64;
            int nkPer   = (nkTotal + SPLIT1F - 1) / SPLIT1F;
            dim3 grid(D1/64, (n_rois + 63)/64, SPLIT1F);
            mfma_gemm<2><<<grid, 256, 0, stream>>>(pooledB, w1B, nullptr, P,
                                                   n_rois, D1, PK, nkPer, nkTotal);
            int MN = n_rois * D1;
            reduce_relu_bf16<<<(MN/4 + 255)/256, 256, 0, stream>>>(P, b1, Y, MN, D1, SPLIT1F);
        }
        {
            int nkTotal = D1 / 64;
            int nkPer   = nkTotal / SPLIT2;
            dim3 grid(D1/64, (n_rois + 63)/64, SPLIT2);
            mfma_gemm<2><<<grid, 256, 0, stream>>>(Y, w2B, nullptr, P2,
                                                   n_rois, D1, D1, nkPer, nkTotal);
            int MN = n_rois * D1;
            reduce_heads<<<n_rois, 256, 0, stream>>>(P2, b2, SPLIT2, MN,
                w_bbox, b_bbox, w_cls, b_cls, w_reg, b_reg, w_unc, b_unc, out, n_rois);
        }
    } else {
        // ------- fallback: proven 39.1 MB layout -------
        ushort* pooledB = (ushort*)ws;
        ushort* w1B = pooledB + poolB/2;
        ushort* w2B = w1B + w1Bb/2;
        ushort* Y   = w2B + w2Bb/2;
        float*  Z   = (float*)((char*)Y + Yb);

        cvt_bf16<<<((D1*PK/4) + 255)/256, 256, 0, stream>>>(w1, w1B, D1*PK/4);
        cvt_bf16<<<((D1*D1/4) + 255)/256, 256, 0, stream>>>(w2, w2B, D1*D1/4);
        {
            int total = n_rois * PK;
            roi_align_nchw<<<(total + 255)/256, 256, 0, stream>>>(
                f0, f1, f2, f3, rois, pooledB, n_rois);
        }
        {
            dim3 grid(D1/64, (n_rois + 63)/64);
            mfma_gemm<1><<<grid, 256, 0, stream>>>(pooledB, w1B, b1, Y,
                                                   n_rois, D1, PK, PK/64, PK/64);
        }
        {
            dim3 grid(D1/64, (n_rois + 63)/64);
            mfma_gemm<0><<<grid, 256, 0, stream>>>(Y, w2B, b2, Z,
                                                   n_rois, D1, D1, D1/64, D1/64);
        }
        heads_kernel<<<(n_rois*14 + 255)/256, 256, 0, stream>>>(
            Z, w_bbox, b_bbox, w_cls, b_cls, w_reg, b_reg, w_unc, b_unc, out, n_rois);
    }
}

// Round 6
// 225.486 us; speedup vs baseline: 1.0175x; 1.0175x over previous
//
#include <hip/hip_runtime.h>
#include <hip/hip_bf16.h>
#include <cstddef>
#include <cstdint>

typedef __attribute__((ext_vector_type(8))) short short8;
typedef __attribute__((ext_vector_type(16))) float float16;

#define C_CH 192
#define PK   9408      // C_CH * 49
#define D1   768

__device__ __forceinline__ ushort f2bf(float v) {
    return __builtin_bit_cast(unsigned short, __float2bfloat16(v));
}

// async global->LDS, 16B per lane, wave-uniform LDS base + lane*16 dest
__device__ __forceinline__ void gload16(const void* g, void* l) {
    __builtin_amdgcn_global_load_lds(
        (const __attribute__((address_space(1))) void*)g,
        (__attribute__((address_space(3))) void*)l, 16, 0, 0);
}

// ---------------------------------------------------------------------------
// fp32 -> bf16 conversion (standalone, used by fallback paths)
// ---------------------------------------------------------------------------
__global__ __launch_bounds__(256) void cvt_bf16_2(
    const float* __restrict__ in1, ushort* __restrict__ out1, int n4_1,
    const float* __restrict__ in2, ushort* __restrict__ out2, int n4_2)
{
    int i = blockIdx.x * 256 + threadIdx.x;
    const float* in; ushort* out;
    if (i < n4_1) { in = in1; out = out1; }
    else          { i -= n4_1; if (i >= n4_2) return; in = in2; out = out2; }
    float4 v = ((const float4*)in)[i];
    ushort4 o;
    o.x = f2bf(v.x); o.y = f2bf(v.y); o.z = f2bf(v.z); o.w = f2bf(v.w);
    ((ushort4*)out)[i] = o;
}

__global__ __launch_bounds__(256) void cvt_bf16(const float* __restrict__ in,
                                                ushort* __restrict__ out, int n4)
{
    int i = blockIdx.x * 256 + threadIdx.x;
    if (i >= n4) return;
    float4 v = ((const float4*)in)[i];
    ushort4 o;
    o.x = f2bf(v.x); o.y = f2bf(v.y); o.z = f2bf(v.z); o.w = f2bf(v.w);
    ((ushort4*)out)[i] = o;
}

// ---------------------------------------------------------------------------
// Fused pre-pass: all 4 pyramid levels NCHW(fp32) -> NHWC(bf16) with
// coalesced dword stores, PLUS fp32->bf16 conversion of both weight
// tensors in extra blocks of the same grid. One launch.
// ---------------------------------------------------------------------------
__global__ __launch_bounds__(256) void fused_pre(
    const float* __restrict__ f0, const float* __restrict__ f1,
    const float* __restrict__ f2, const float* __restrict__ f3,
    ushort* __restrict__ o0, ushort* __restrict__ o1,
    ushort* __restrict__ o2, ushort* __restrict__ o3,
    const float* __restrict__ w1src, ushort* __restrict__ w1dst, int n41,
    const float* __restrict__ w2src, ushort* __restrict__ w2dst, int n42,
    int nTrans)
{
    __shared__ unsigned int sm[96][33];   // 96 channel-pairs x 32 px (+1 pad)

    int bx = blockIdx.x;
    if (bx >= nTrans) {
        int i = (bx - nTrans) * 256 + threadIdx.x;
        const float* in; ushort* out;
        if (i < n41) { in = w1src; out = w1dst; }
        else         { i -= n41; if (i >= n42) return; in = w2src; out = w2dst; }
        float4 v = ((const float4*)in)[i];
        ushort4 o;
        o.x = f2bf(v.x); o.y = f2bf(v.y); o.z = f2bf(v.z); o.w = f2bf(v.w);
        ((ushort4*)out)[i] = o;
        return;
    }

    int b = bx / 680;
    int t = bx - b * 680;
    const float* in; ushort* out; int HW, hw0;
    if      (t < 512) { in = f0; out = o0; HW = 16384; hw0 = t * 32; }
    else if (t < 640) { in = f1; out = o1; HW = 4096;  hw0 = (t - 512) * 32; }
    else if (t < 672) { in = f2; out = o2; HW = 1024;  hw0 = (t - 640) * 32; }
    else              { in = f3; out = o3; HW = 256;   hw0 = (t - 672) * 32; }

    int tx = threadIdx.x & 31;
    int ty = threadIdx.x >> 5;    // 0..7

    const float* ip = in + (size_t)b * C_CH * HW + hw0;
    #pragma unroll
    for (int it = 0; it < 12; ++it) {          // 96 pairs = 12 * 8
        int cp = it * 8 + ty;
        float v0 = ip[(size_t)(2 * cp)     * HW + tx];
        float v1 = ip[(size_t)(2 * cp + 1) * HW + tx];
        sm[cp][tx] = (unsigned int)f2bf(v0) | ((unsigned int)f2bf(v1) << 16);
    }
    __syncthreads();

    unsigned int* op = (unsigned int*)(out + ((size_t)b * HW + hw0) * C_CH);
    #pragma unroll
    for (int it = 0; it < 12; ++it) {          // 32 px * 96 dwords = 12 * 256
        int idx = it * 256 + (int)threadIdx.x;
        int r = idx / 96;
        int p = idx - r * 96;
        op[idx] = sm[p][r];
    }
}

// ---------------------------------------------------------------------------
// RoIAlign gather from NHWC bf16, one block per RoI, DEDUPED taps.
// Bilinear weights are separable: y depends only on (bin-i, sy), x only on
// (bin-j, sx). Per bin we build a distinct-row list (<=4, typ. 2-3) and a
// distinct-col list (<=4) with merged weights; bin value = weighted outer
// product over distinct pixels. Cuts L2/L3 tap traffic ~2.5x vs 16 fixed
// taps (the gather is cache-BW-bound; bytes, not instructions — r3/r4 A/B).
// 384 threads = 16 bin-groups x 24 channel-oct threads (float4 taps).
// ---------------------------------------------------------------------------
__global__ __launch_bounds__(384, 3) void roi_gather(
    const ushort* __restrict__ n0p, const ushort* __restrict__ n1p,
    const ushort* __restrict__ n2p, const ushort* __restrict__ n3p,
    const float* __restrict__ rois, ushort* __restrict__ pooled)
{
    __shared__ int    s_off[49][2][4];   // [bin][0=row,1=col][entry] byte offsets
    __shared__ float  s_wt [49][2][4];   // merged weights (0.5*v*l factors)
    __shared__ int    s_cnt[49][2];
    __shared__ ushort s_out[PK];         // 192 channels x 49 bins

    const int n   = blockIdx.x;
    const int tid = threadIdx.x;

    float by1 = rois[n*5+0], bx1 = rois[n*5+1];
    float by2 = rois[n*5+2], bx2 = rois[n*5+3];
    int   b   = (int)rois[n*5+4];

    float hh = by2 - by1, ww = bx2 - bx1;
    int lvl = (int)rintf(4.0f + log2f(sqrtf(hh * ww)));
    lvl = min(max(lvl, 0), 3);

    const ushort* fm; int H;
    if      (lvl == 0) { fm = n0p; H = 128; }
    else if (lvl == 1) { fm = n1p; H = 64;  }
    else if (lvl == 2) { fm = n2p; H = 32;  }
    else               { fm = n3p; H = 16;  }
    float Hf = (float)H;

    float y1p = by1 * Hf, x1p = bx1 * Hf;
    float y2p = by2 * Hf, x2p = bx2 * Hf;
    float bin_h = fmaxf(y2p - y1p, 1.0f) * (1.0f / 7.0f);
    float bin_w = fmaxf(x2p - x1p, 1.0f) * (1.0f / 7.0f);

    // scalarize base pointer (block-uniform): SGPR base + 32-bit voffset loads
    uintptr_t bp = (uintptr_t)(fm + (size_t)b * H * H * C_CH);
    unsigned int blo = __builtin_amdgcn_readfirstlane((unsigned int)bp);
    unsigned int bhi = __builtin_amdgcn_readfirstlane((unsigned int)(bp >> 32));
    const char* sbase = (const char*)((((uintptr_t)bhi) << 32) | blo);

    // Setup: thread (bin, dim) builds the merged 1-D tap list for its axis.
    if (tid < 98) {
        int bin = tid >> 1, dim = tid & 1;
        int bi  = bin / 7, bj = bin - bi * 7;
        int pos   = dim ? bj : bi;
        float org = dim ? x1p : y1p;
        float bsz = dim ? bin_w : bin_h;

        int   idxs[4];
        float wts[4];
        int   cnt = 0;
        #pragma unroll
        for (int s = 0; s < 2; ++s) {
            float g  = (float)pos + 0.25f + 0.5f * (float)s;
            float v  = org + g * bsz;
            bool  ok = (v >= -1.0f) && (v <= Hf);
            float vc = fminf(fmaxf(v, 0.0f), Hf - 1.0f);
            int   p0 = (int)floorf(vc);
            float l  = vc - (float)p0;
            int   p1 = min(p0 + 1, H - 1);
            float w0 = ok ? 0.5f * (1.0f - l) : 0.0f;
            float w1 = ok ? 0.5f * l          : 0.0f;
            // merge-add (p0,w0) and (p1,w1); drop zero weights
            #pragma unroll
            for (int e = 0; e < 2; ++e) {
                int   pi = e ? p1 : p0;
                float wi = e ? w1 : w0;
                if (wi != 0.0f) {
                    bool merged = false;
                    for (int k = 0; k < cnt; ++k)
                        if (idxs[k] == pi) { wts[k] += wi; merged = true; break; }
                    if (!merged) { idxs[cnt] = pi; wts[cnt] = wi; ++cnt; }
                }
            }
        }
        int stride = dim ? (C_CH * 2) : (H * C_CH * 2);
        for (int k = 0; k < cnt; ++k) {
            s_off[bin][dim][k] = idxs[k] * stride;
            s_wt [bin][dim][k] = wts[k];
        }
        s_cnt[bin][dim] = cnt;
    }
    __syncthreads();

    const int grp = tid / 24;            // 0..15 bin-group
    const int ci  = tid - grp * 24;      // channel-oct index
    const int cl  = ci * 8;              // channel in [0,192)
    const int c16 = ci * 16;             // byte offset of channel oct
    const int bin_lo = (grp * 49) >> 4;  // 3 or 4 bins per group
    const int bin_hi = ((grp + 1) * 49) >> 4;

    for (int bin = bin_lo; bin < bin_hi; ++bin) {
        const int nr = s_cnt[bin][0];
        const int nc = s_cnt[bin][1];
        float a[8];
        #pragma unroll
        for (int k = 0; k < 8; ++k) a[k] = 0.0f;

        #pragma unroll
        for (int r = 0; r < 4; ++r) {
            if (r >= nr) break;                      // uniform per bin-group
            const char* rp = sbase + (s_off[bin][0][r] + c16);
            const float rw = s_wt[bin][0][r];
            #pragma unroll
            for (int c = 0; c < 4; ++c) {
                if (c >= nc) break;
                float4 u = *(const float4*)(rp + s_off[bin][1][c]);
                float  w = rw * s_wt[bin][1][c];
                unsigned int u0 = __builtin_bit_cast(unsigned int, u.x);
                unsigned int u1 = __builtin_bit_cast(unsigned int, u.y);
                unsigned int u2 = __builtin_bit_cast(unsigned int, u.z);
                unsigned int u3 = __builtin_bit_cast(unsigned int, u.w);
                a[0] = fmaf(__builtin_bit_cast(float, u0 << 16),         w, a[0]);
                a[1] = fmaf(__builtin_bit_cast(float, u0 & 0xffff0000u), w, a[1]);
                a[2] = fmaf(__builtin_bit_cast(float, u1 << 16),         w, a[2]);
                a[3] = fmaf(__builtin_bit_cast(float, u1 & 0xffff0000u), w, a[3]);
                a[4] = fmaf(__builtin_bit_cast(float, u2 << 16),         w, a[4]);
                a[5] = fmaf(__builtin_bit_cast(float, u2 & 0xffff0000u), w, a[5]);
                a[6] = fmaf(__builtin_bit_cast(float, u3 << 16),         w, a[6]);
                a[7] = fmaf(__builtin_bit_cast(float, u3 & 0xffff0000u), w, a[7]);
            }
        }
        #pragma unroll
        for (int k = 0; k < 8; ++k)
            s_out[(cl + k) * 49 + bin] = f2bf(a[k]);
    }
    __syncthreads();

    unsigned int* po = (unsigned int*)(pooled + (size_t)n * PK);
    const unsigned int* so = (const unsigned int*)s_out;
    for (int idx = tid; idx < PK / 2; idx += 384) po[idx] = so[idx];
}

// ---------------------------------------------------------------------------
// RoIAlign from NCHW fp32 (fallback path, proven): 1 thread / output element
// ---------------------------------------------------------------------------
__global__ __launch_bounds__(256) void roi_align_nchw(
    const float* __restrict__ f0, const float* __restrict__ f1,
    const float* __restrict__ f2, const float* __restrict__ f3,
    const float* __restrict__ rois, ushort* __restrict__ pooled, int n_rois)
{
    int idx = blockIdx.x * 256 + threadIdx.x;
    if (idx >= n_rois * PK) return;
    int n  = idx / PK;
    int r  = idx - n * PK;
    int c  = r / 49;
    int ij = r - c * 49;
    int i  = ij / 7;
    int j  = ij - i * 7;

    float by1 = rois[n*5+0], bx1 = rois[n*5+1];
    float by2 = rois[n*5+2], bx2 = rois[n*5+3];
    int   b   = (int)rois[n*5+4];

    float hh = by2 - by1, ww = bx2 - bx1;
    int lvl = (int)rintf(4.0f + log2f(sqrtf(hh * ww)));
    lvl = min(max(lvl, 0), 3);

    const float* fmap; int H;
    if      (lvl == 0) { fmap = f0; H = 128; }
    else if (lvl == 1) { fmap = f1; H = 64;  }
    else if (lvl == 2) { fmap = f2; H = 32;  }
    else               { fmap = f3; H = 16;  }
    float Hf = (float)H;

    float y1p = by1 * Hf, x1p = bx1 * Hf;
    float bin_h = fmaxf(by2 * Hf - y1p, 1.0f) * (1.0f / 7.0f);
    float bin_w = fmaxf(bx2 * Hf - x1p, 1.0f) * (1.0f / 7.0f);

    const float* base = fmap + ((size_t)b * C_CH + c) * (size_t)(H * H);

    float acc = 0.0f;
    #pragma unroll
    for (int sy = 0; sy < 2; ++sy) {
        float y  = y1p + ((float)i + 0.25f + 0.5f * (float)sy) * bin_h;
        bool  vy = (y >= -1.0f) && (y <= Hf);
        float yc = fminf(fmaxf(y, 0.0f), Hf - 1.0f);
        int   y0 = (int)floorf(yc);
        float ly = yc - (float)y0;
        int   y1i = min(y0 + 1, H - 1);
        #pragma unroll
        for (int sx = 0; sx < 2; ++sx) {
            float x  = x1p + ((float)j + 0.25f + 0.5f * (float)sx) * bin_w;
            bool  vx = (x >= -1.0f) && (x <= Hf);
            float xc = fminf(fmaxf(x, 0.0f), Hf - 1.0f);
            int   x0 = (int)floorf(xc);
            float lx = xc - (float)x0;
            int   x1i = min(x0 + 1, H - 1);
            if (vy && vx) {
                float v = base[y0 * H + x0 ] * (1.0f - ly) * (1.0f - lx)
                        + base[y0 * H + x1i] * (1.0f - ly) * lx
                        + base[y1i * H + x0 ] * ly * (1.0f - lx)
                        + base[y1i * H + x1i] * ly * lx;
                acc += v;
            }
        }
    }
    pooled[idx] = f2bf(acc * 0.25f);
}

// ---------------------------------------------------------------------------
// bf16 MFMA GEMM, 64x64 tile (proven, reg-staged). MODE 0: fp32 out
// bias+relu. MODE 1: bf16 out bias+relu. MODE 2: fp32 partial split-K.
// ---------------------------------------------------------------------------
template<int MODE>
__global__ __launch_bounds__(256) void mfma_gemm(
    const ushort* __restrict__ A, const ushort* __restrict__ W,
    const float* __restrict__ bias, void* __restrict__ outp,
    int M, int N, int K, int nkPer, int nkTotal)
{
    __shared__ char ldsA[2][8192];
    __shared__ char ldsB[2][8192];

    const int t    = threadIdx.x;
    const int lane = t & 63;
    const int wave = t >> 6;
    const int wm = wave >> 1, wn = wave & 1;

    const int m0 = blockIdx.y * 64;
    const int n0 = blockIdx.x * 64;
    const int kb = (MODE == 2) ? blockIdx.z * nkPer : 0;
    const int nk = (MODE == 2) ? min(nkPer, nkTotal - kb) : nkPer;

    const int ks   = t & 3;
    const int mrow = t >> 2;
    const int g    = mrow >> 5;
    const int rw   = mrow & 31;
    const int lof0 = ks*2048 + g*1024 + ((     rw) ^ (ks<<2))*16;
    const int lof1 = ks*2048 + g*1024 + ((32 + rw) ^ (ks<<2))*16;

    const int arow = min(m0 + mrow, M-1);
    const int brow = n0 + mrow;
    const ushort* ap = A + (size_t)arow * K + (size_t)kb * 64 + ks*16;
    const ushort* bp = W + (size_t)brow * K + (size_t)kb * 64 + ks*16;

    float4 ra0, ra1, rb0, rb1;
    float4 qa0, qa1, qb0, qb1;

    ra0 = ((const float4*)ap)[0]; ra1 = ((const float4*)ap)[1];
    rb0 = ((const float4*)bp)[0]; rb1 = ((const float4*)bp)[1];
    *(float4*)&ldsA[0][lof0] = ra0; *(float4*)&ldsA[0][lof1] = ra1;
    *(float4*)&ldsB[0][lof0] = rb0; *(float4*)&ldsB[0][lof1] = rb1;
    {
        int k1 = min(1, nk - 1);
        const ushort* ap1 = ap + (size_t)k1 * 64;
        const ushort* bp1 = bp + (size_t)k1 * 64;
        ra0 = ((const float4*)ap1)[0]; ra1 = ((const float4*)ap1)[1];
        rb0 = ((const float4*)bp1)[0]; rb1 = ((const float4*)bp1)[1];
    }
    __syncthreads();

    float16 acc = {};

    for (int kt = 0; kt < nk; ++kt) {
        {
            int k2 = min(kt + 2, nk - 1);
            const ushort* ap2 = ap + (size_t)k2 * 64;
            const ushort* bp2 = bp + (size_t)k2 * 64;
            qa0 = ((const float4*)ap2)[0]; qa1 = ((const float4*)ap2)[1];
            qb0 = ((const float4*)bp2)[0]; qb1 = ((const float4*)bp2)[1];
        }
        if (kt + 1 < nk) {
            char* dA = ldsA[(kt+1)&1]; char* dB = ldsB[(kt+1)&1];
            *(float4*)&dA[lof0] = ra0; *(float4*)&dA[lof1] = ra1;
            *(float4*)&dB[lof0] = rb0; *(float4*)&dB[lof1] = rb1;
        }
        const char* sA = ldsA[kt&1]; const char* sB = ldsB[kt&1];
        #pragma unroll
        for (int s = 0; s < 4; ++s) {
            int ro = s*2048 + (lane ^ (s<<2))*16;
            short8 af = *(const short8*)&sA[wm*1024 + ro];
            short8 bf = *(const short8*)&sB[wn*1024 + ro];
            acc = __builtin_amdgcn_mfma_f32_32x32x16_bf16(af, bf, acc, 0, 0, 0);
        }
        __syncthreads();
        ra0 = qa0; ra1 = qa1; rb0 = qb0; rb1 = qb1;
    }

    const int col   = lane & 31;
    const int rbase = 4 * (lane >> 5);
    const int nG    = n0 + wn*32 + col;

    if (MODE == 2) {
        float* O = (float*)outp + (size_t)blockIdx.z * M * N;
        #pragma unroll
        for (int r = 0; r < 16; ++r) {
            int row = (r & 3) + 8*(r >> 2) + rbase;
            int mG  = m0 + wm*32 + row;
            if (mG < M) O[(size_t)mG * N + nG] = acc[r];
        }
    } else if (MODE == 1) {
        const float bv = bias[nG];
        ushort* O = (ushort*)outp;
        #pragma unroll
        for (int r = 0; r < 16; ++r) {
            int row = (r & 3) + 8*(r >> 2) + rbase;
            int mG  = m0 + wm*32 + row;
            if (mG < M) O[(size_t)mG * N + nG] = f2bf(fmaxf(acc[r] + bv, 0.0f));
        }
    } else {
        const float bv = bias[nG];
        float* O = (float*)outp;
        #pragma unroll
        for (int r = 0; r < 16; ++r) {
            int row = (r & 3) + 8*(r >> 2) + rbase;
            int mG  = m0 + wm*32 + row;
            if (mG < M) O[(size_t)mG * N + nG] = fmaxf(acc[r] + bv, 0.0f);
        }
    }
}

// ---------------------------------------------------------------------------
// bf16 MFMA GEMM, 128x128 tile, BK=64, double-buffered LDS.
// Staging via global_load_lds dwordx4 DMA (m97 pattern): LDS dest is linear
// per 1KB segment; the XOR swizzle is baked into the per-lane GLOBAL source
// address (write perm == read perm, rule #21). fp32 partial out, split-K.
// ---------------------------------------------------------------------------
__global__ __launch_bounds__(256) void mfma_gemm128(
    const ushort* __restrict__ A, const ushort* __restrict__ W,
    void* __restrict__ outp, int M, int N, int K, int nkPer, int nkTotal)
{
    __shared__ char ldsA[2][16384];
    __shared__ char ldsB[2][16384];

    const int t    = threadIdx.x;
    const int lane = t & 63;
    const int wave = t >> 6;
    const int wm = wave >> 1, wn = wave & 1;

    const int m0 = blockIdx.y * 128;
    const int n0 = blockIdx.x * 128;
    const int kb = blockIdx.z * nkPer;
    const int nk = min(nkPer, nkTotal - kb);

    int aoff[4], boff[4], lofs[4];
    #pragma unroll
    for (int i = 0; i < 4; ++i) {
        int sid = wave * 4 + i;
        int ks = sid >> 2, h = (sid >> 1) & 1, g = sid & 1;
        int swz = ks << 2;
        int rl  = h * 64 + g * 32 + ((lane & 31) ^ swz);
        int ko  = ks * 16 + (lane >> 5) * 8;
        int arow = min(m0 + rl, M - 1);
        int brow = n0 + rl;          // N grid is exact
        aoff[i] = arow * K + ko;
        boff[i] = brow * K + ko;
        lofs[i] = sid * 1024;
    }
    const size_t kbase = (size_t)kb * 64;

    #define STAGE128(buf, kt)                                                  \
        do {                                                                   \
            const ushort* Ab_ = A + kbase + (size_t)(kt) * 64;                 \
            const ushort* Wb_ = W + kbase + (size_t)(kt) * 64;                 \
            _Pragma("unroll")                                                  \
            for (int i_ = 0; i_ < 4; ++i_) {                                   \
                gload16(Ab_ + aoff[i_], &ldsA[buf][lofs[i_]]);                 \
                gload16(Wb_ + boff[i_], &ldsB[buf][lofs[i_]]);                 \
            }                                                                  \
        } while (0)

    STAGE128(0, 0);
    __syncthreads();

    float16 acc00 = {}, acc01 = {}, acc10 = {}, acc11 = {};

    for (int kt = 0; kt < nk; ++kt) {
        if (kt + 1 < nk) STAGE128((kt + 1) & 1, kt + 1);
        const char* sA = ldsA[kt & 1];
        const char* sB = ldsB[kt & 1];
        #pragma unroll
        for (int s = 0; s < 4; ++s) {
            int ro = s*4096 + (lane ^ (s<<2))*16;
            short8 a0 = *(const short8*)&sA[wm*2048        + ro];
            short8 a1 = *(const short8*)&sA[wm*2048 + 1024 + ro];
            short8 b0 = *(const short8*)&sB[wn*2048        + ro];
            short8 b1 = *(const short8*)&sB[wn*2048 + 1024 + ro];
            acc00 = __builtin_amdgcn_mfma_f32_32x32x16_bf16(a0, b0, acc00, 0, 0, 0);
            acc01 = __builtin_amdgcn_mfma_f32_32x32x16_bf16(a0, b1, acc01, 0, 0, 0);
            acc10 = __builtin_amdgcn_mfma_f32_32x32x16_bf16(a1, b0, acc10, 0, 0, 0);
            acc11 = __builtin_amdgcn_mfma_f32_32x32x16_bf16(a1, b1, acc11, 0, 0, 0);
        }
        __syncthreads();
    }
    #undef STAGE128

    const int col   = lane & 31;
    const int rbase = 4 * (lane >> 5);
    float* O = (float*)outp + (size_t)blockIdx.z * M * N;

    const int mb0 = m0 + wm*64;
    const int nb0 = n0 + wn*64;
    #pragma unroll
    for (int r = 0; r < 16; ++r) {
        int row = (r & 3) + 8*(r >> 2) + rbase;
        int mG0 = mb0 + row;
        int mG1 = mb0 + 32 + row;
        int nG0 = nb0 + col;
        int nG1 = nb0 + 32 + col;
        if (mG0 < M) {
            O[(size_t)mG0 * N + nG0] = acc00[r];
            O[(size_t)mG0 * N + nG1] = acc01[r];
        }
        if (mG1 < M) {
            O[(size_t)mG1 * N + nG0] = acc10[r];
            O[(size_t)mG1 * N + nG1] = acc11[r];
        }
    }
}

// ---------------------------------------------------------------------------
// FC1 split-K reduce -> bf16 Y
// ---------------------------------------------------------------------------
__global__ __launch_bounds__(256) void reduce_relu_bf16(
    const float* __restrict__ P, const float* __restrict__ bias,
    ushort* __restrict__ Y, int MN, int N, int S)
{
    int idx = blockIdx.x * 256 + threadIdx.x;
    if (idx >= MN / 4) return;
    float4 s = ((const float4*)P)[idx];
    for (int k = 1; k < S; ++k) {
        float4 p = ((const float4*)(P + (size_t)k * MN))[idx];
        s.x += p.x; s.y += p.y; s.z += p.z; s.w += p.w;
    }
    int n4 = idx % (N / 4);
    float4 bv = ((const float4*)bias)[n4];
    ushort4 o;
    o.x = f2bf(fmaxf(s.x + bv.x, 0.0f));
    o.y = f2bf(fmaxf(s.y + bv.y, 0.0f));
    o.z = f2bf(fmaxf(s.z + bv.z, 0.0f));
    o.w = f2bf(fmaxf(s.w + bv.w, 0.0f));
    ((ushort4*)Y)[idx] = o;
}

// ---------------------------------------------------------------------------
// Fused FC2-reduce + relu + heads. One block per RoI (256 threads).
// ---------------------------------------------------------------------------
__global__ __launch_bounds__(256) void reduce_heads(
    const float* __restrict__ P2, const float* __restrict__ b2, int S, int MN,
    const float* __restrict__ w_bbox, const float* __restrict__ b_bbox,
    const float* __restrict__ w_cls,  const float* __restrict__ b_cls,
    const float* __restrict__ w_reg,  const float* __restrict__ b_reg,
    const float* __restrict__ w_unc,  const float* __restrict__ b_unc,
    float* __restrict__ out, int n_rois)
{
    __shared__ float zrow[D1];
    const int m   = blockIdx.x;
    const int tid = threadIdx.x;

    const float* Pm = P2 + (size_t)m * D1;
    #pragma unroll
    for (int r = 0; r < 3; ++r) {               // 768 = 3 * 256
        int k = r * 256 + tid;
        float v = Pm[k];
        for (int s = 1; s < S; ++s) v += Pm[(size_t)s * MN + k];
        zrow[k] = fmaxf(v + b2[k], 0.0f);
    }
    __syncthreads();

    const int wave = tid >> 6;
    const int lane = tid & 63;
    for (int o = wave; o < 14; o += 4) {
        const float* w; float bb;
        if      (o < 8)  { w = w_bbox + o * D1;        bb = b_bbox[o]; }
        else if (o < 10) { w = w_cls  + (o - 8) * D1;  bb = b_cls[o - 8]; }
        else if (o < 12) { w = w_reg  + (o - 10) * D1; bb = b_reg[o - 10]; }
        else             { w = w_unc  + (o - 12) * D1; bb = b_unc[o - 12]; }
        float p = 0.0f;
        #pragma unroll
        for (int r = 0; r < 12; ++r) {          // 768 = 12 * 64
            int k = r * 64 + lane;
            p = fmaf(zrow[k], w[k], p);
        }
        #pragma unroll
        for (int d = 32; d >= 1; d >>= 1) p += __shfl_down(p, d, 64);
        if (lane == 0) {
            int off;
            int clsOff = n_rois * 8;
            int regOff = n_rois * 10;
            if      (o < 8)  off = m * 8 + o;
            else if (o < 10) off = clsOff + m * 2 + (o - 8);
            else if (o < 12) off = regOff + m * 4 + (o - 10) * 2;
            else             off = regOff + m * 4 + (o - 12) * 2 + 1;
            out[off] = p + bb;
        }
    }
}

// ---------------------------------------------------------------------------
// Heads (fallback path)
// ---------------------------------------------------------------------------
__global__ __launch_bounds__(256) void heads_kernel(
    const float* __restrict__ Z,
    const float* __restrict__ w_bbox, const float* __restrict__ b_bbox,
    const float* __restrict__ w_cls,  const float* __restrict__ b_cls,
    const float* __restrict__ w_reg,  const float* __restrict__ b_reg,
    const float* __restrict__ w_unc,  const float* __restrict__ b_unc,
    float* __restrict__ out, int n_rois)
{
    int idx = blockIdx.x * 256 + threadIdx.x;
    if (idx >= n_rois * 14) return;
    int n = idx / 14;
    int o = idx - n * 14;

    const float* w; float bb;
    if      (o < 8)  { w = w_bbox + o * D1;        bb = b_bbox[o]; }
    else if (o < 10) { w = w_cls  + (o - 8) * D1;  bb = b_cls[o - 8]; }
    else if (o < 12) { w = w_reg  + (o - 10) * D1; bb = b_reg[o - 10]; }
    else             { w = w_unc  + (o - 12) * D1; bb = b_unc[o - 12]; }

    const float* z = Z + (size_t)n * D1;
    float s = bb;
    for (int k = 0; k < D1; k += 4) {
        float4 zv = *(const float4*)(z + k);
        float4 wv = *(const float4*)(w + k);
        s = fmaf(zv.x, wv.x, s);
        s = fmaf(zv.y, wv.y, s);
        s = fmaf(zv.z, wv.z, s);
        s = fmaf(zv.w, wv.w, s);
    }

    int off;
    int clsOff = n_rois * 8;
    int regOff = n_rois * 10;
    if      (o < 8)  off = n * 8 + o;
    else if (o < 10) off = clsOff + n * 2 + (o - 8);
    else if (o < 12) off = regOff + n * 4 + (o - 10) * 2;
    else             off = regOff + n * 4 + (o - 12) * 2 + 1;
    out[off] = s;
}

// ---------------------------------------------------------------------------
extern "C" void kernel_launch(void* const* d_in, const int* in_sizes, int n_in,
                              void* d_out, int out_size, void* d_ws, size_t ws_size,
                              hipStream_t stream)
{
    const float* f0   = (const float*)d_in[0];
    const float* f1   = (const float*)d_in[1];
    const float* f2   = (const float*)d_in[2];
    const float* f3   = (const float*)d_in[3];
    const float* rois = (const float*)d_in[4];
    const float* w1   = (const float*)d_in[5];
    const float* b1   = (const float*)d_in[6];
    const float* w2   = (const float*)d_in[7];
    const float* b2   = (const float*)d_in[8];
    const float* w_bbox = (const float*)d_in[9];
    const float* b_bbox = (const float*)d_in[10];
    const float* w_cls  = (const float*)d_in[11];
    const float* b_cls  = (const float*)d_in[12];
    const float* w_reg  = (const float*)d_in[13];
    const float* b_reg  = (const float*)d_in[14];
    const float* w_unc  = (const float*)d_in[15];
    const float* b_unc  = (const float*)d_in[16];
    float* out = (float*)d_out;

    const int n_rois = in_sizes[4] / 5;                  // 1000
    const int B      = in_sizes[0] / (C_CH * 128 * 128); // 4

    const size_t nh0B = (size_t)B * 16384 * C_CH * 2;
    const size_t nh1B = (size_t)B * 4096  * C_CH * 2;
    const size_t nh2B = (size_t)B * 1024  * C_CH * 2;
    const size_t nh3B = (size_t)B * 256   * C_CH * 2;
    const size_t nhAll = nh0B + nh1B + nh2B + nh3B;      // 33.4 MB
    const size_t poolB = (size_t)n_rois * PK * 2;        // 18.8 MB
    const size_t w1Bb  = (size_t)D1 * PK * 2;            // 14.45 MB
    const size_t w2Bb  = (size_t)D1 * D1 * 2;
    const size_t Yb    = (size_t)n_rois * D1 * 2;
    const size_t Zb    = (size_t)n_rois * D1 * 4;
    const size_t smallB = w2Bb + Yb + Zb;

    const int SPLIT1  = 10;  // FC1 (128-tile): nkPer=15 -> 15x9 + 12 (147)
    const int SPLIT1F = 5;   // FC1 (64-tile fallback plan)
    const int SPLIT2  = 2;   // FC2: 6+6

    const size_t P1b   = (size_t)SPLIT1 * n_rois * D1 * 4;   // 30.7 MB (<= nhAll)
    const size_t needX2 = nhAll + poolB + w1Bb + w2Bb + Yb;  // ~69.4 MB
    const size_t needX  = nhAll + poolB + smallB;            // ~58.0 MB (proven)

    char* ws = (char*)d_ws;

    int n41 = D1*PK/4, n42 = D1*D1/4;

    if (ws_size >= needX2) {
        // ---------------- Plan X2: fused pre-pass + gload_lds 128-tile FC1 -
        ushort* nh0 = (ushort*)ws;
        ushort* nh1 = nh0 + nh0B/2;
        ushort* nh2 = nh1 + nh1B/2;
        ushort* nh3 = nh2 + nh2B/2;
        ushort* pooledB = (ushort*)(ws + nhAll);
        ushort* w1B = (ushort*)(ws + nhAll + poolB);
        ushort* w2B = (ushort*)(ws + nhAll + poolB + w1Bb);
        ushort* Y   = (ushort*)(ws + nhAll + poolB + w1Bb + w2Bb);
        float*  P   = (float*)ws;                // alias: nh dead after gather
        float*  P2  = (float*)(ws + P1b);        // alias: pooled dead after FC1

        int nTrans = 680 * B;
        int nCvt   = (n41 + n42 + 255) / 256;
        fused_pre<<<nTrans + nCvt, 256, 0, stream>>>(
            f0, f1, f2, f3, nh0, nh1, nh2, nh3,
            w1, w1B, n41, w2, w2B, n42, nTrans);

        roi_gather<<<n_rois, 384, 0, stream>>>(nh0, nh1, nh2, nh3, rois, pooledB);

        {
            int nkTotal = PK / 64;                          // 147
            int nkPer   = (nkTotal + SPLIT1 - 1) / SPLIT1;  // 15
            dim3 grid(D1/128, (n_rois + 127)/128, SPLIT1);
            mfma_gemm128<<<grid, 256, 0, stream>>>(pooledB, w1B, P,
                                                   n_rois, D1, PK, nkPer, nkTotal);
            int MN = n_rois * D1;
            reduce_relu_bf16<<<(MN/4 + 255)/256, 256, 0, stream>>>(P, b1, Y, MN, D1, SPLIT1);
        }
        {
            int nkTotal = D1 / 64;                          // 12
            int nkPer   = nkTotal / SPLIT2;                 // 6
            dim3 grid(D1/64, (n_rois + 63)/64, SPLIT2);
            mfma_gemm<2><<<grid, 256, 0, stream>>>(Y, w2B, nullptr, P2,
                                                   n_rois, D1, D1, nkPer, nkTotal);
            int MN = n_rois * D1;
            reduce_heads<<<n_rois, 256, 0, stream>>>(P2, b2, SPLIT2, MN,
                w_bbox, b_bbox, w_cls, b_cls, w_reg, b_reg, w_unc, b_unc, out, n_rois);
        }
    } else if (ws_size >= needX) {
        // ---------------- Plan X (previous proven layout) ----------------
        ushort* nh0 = (ushort*)ws;
        ushort* nh1 = nh0 + nh0B/2;
        ushort* nh2 = nh1 + nh1B/2;
        ushort* nh3 = nh2 + nh2B/2;
        ushort* w1B = (ushort*)ws;                  // alias after gather
        float*  P   = (float*)(ws + w1Bb);          // alias after gather
        float*  P2  = (float*)ws;                   // alias after FC1 gemm
        ushort* pooledB = (ushort*)(ws + nhAll);
        ushort* w2B = (ushort*)(ws + nhAll + poolB);
        ushort* Y   = w2B + w2Bb/2;

        int nTrans = 680 * B;
        fused_pre<<<nTrans, 256, 0, stream>>>(
            f0, f1, f2, f3, nh0, nh1, nh2, nh3,
            w1, (ushort*)nullptr, 0, w2, (ushort*)nullptr, 0, nTrans);
        roi_gather<<<n_rois, 384, 0, stream>>>(nh0, nh1, nh2, nh3, rois, pooledB);
        cvt_bf16_2<<<(n41 + n42 + 255)/256, 256, 0, stream>>>(
            w1, w1B, n41, w2, w2B, n42);
        {
            int nkTotal = PK / 64;
            int nkPer   = (nkTotal + SPLIT1F - 1) / SPLIT1F;
            dim3 grid(D1/64, (n_rois + 63)/64, SPLIT1F);
            mfma_gemm<2><<<grid, 256, 0, stream>>>(pooledB, w1B, nullptr, P,
                                                   n_rois, D1, PK, nkPer, nkTotal);
            int MN = n_rois * D1;
            reduce_relu_bf16<<<(MN/4 + 255)/256, 256, 0, stream>>>(P, b1, Y, MN, D1, SPLIT1F);
        }
        {
            int nkTotal = D1 / 64;
            int nkPer   = nkTotal / SPLIT2;
            dim3 grid(D1/64, (n_rois + 63)/64, SPLIT2);
            mfma_gemm<2><<<grid, 256, 0, stream>>>(Y, w2B, nullptr, P2,
                                                   n_rois, D1, D1, nkPer, nkTotal);
            int MN = n_rois * D1;
            reduce_heads<<<n_rois, 256, 0, stream>>>(P2, b2, SPLIT2, MN,
                w_bbox, b_bbox, w_cls, b_cls, w_reg, b_reg, w_unc, b_unc, out, n_rois);
        }
    } else {
        // ------- fallback: proven 39.1 MB layout -------
        ushort* pooledB = (ushort*)ws;
        ushort* w1B = pooledB + poolB/2;
        ushort* w2B = w1B + w1Bb/2;
        ushort* Y   = w2B + w2Bb/2;
        float*  Z   = (float*)((char*)Y + Yb);

        cvt_bf16<<<((D1*PK/4) + 255)/256, 256, 0, stream>>>(w1, w1B, D1*PK/4);
        cvt_bf16<<<((D1*D1/4) + 255)/256, 256, 0, stream>>>(w2, w2B, D1*D1/4);
        {
            int total = n_rois * PK;
            roi_align_nchw<<<(total + 255)/256, 256, 0, stream>>>(
                f0, f1, f2, f3, rois, pooledB, n_rois);
        }
        {
            dim3 grid(D1/64, (n_rois + 63)/64);
            mfma_gemm<1><<<grid, 256, 0, stream>>>(pooledB, w1B, b1, Y,
                                                   n_rois, D1, PK, PK/64, PK/64);
        }
        {
            dim3 grid(D1/64, (n_rois + 63)/64);
            mfma_gemm<0><<<grid, 256, 0, stream>>>(Y, w2B, b2, Z,
                                                   n_rois, D1, D1, D1/64, D1/64);
        }
        heads_kernel<<<(n_rois*14 + 255)/256, 256, 0, stream>>>(
            Z, w_bbox, b_bbox, w_cls, b_cls, w_reg, b_reg, w_unc, b_unc, out, n_rois);
    }
}